// Round 6
// baseline (1216.389 us; speedup 1.0000x reference)
//
#include <hip/hip_runtime.h>
#include <cstdio>

#define N_TOK 16384
#define CDIM  512

typedef unsigned short ushort_t;
typedef __attribute__((ext_vector_type(8))) __bf16 bf16x8;
typedef __attribute__((ext_vector_type(4))) float f32x4;

// ---------------------------------------------------------------- helpers
__device__ __forceinline__ ushort_t f2bf(float f) {
  union { float f; unsigned u; } v; v.f = f;
  unsigned r = v.u + 0x7FFFu + ((v.u >> 16) & 1u);   // RN-even
  return (ushort_t)(r >> 16);
}
__device__ __forceinline__ float bf2f(ushort_t h) {
  union { unsigned u; float f; } v; v.u = ((unsigned)h) << 16;
  return v.f;
}
// x > 0 guaranteed (relu + 1e-6): x^p = 2^(p*log2(x)) on the HW trans pipe.
__device__ __forceinline__ float fast_pow(float x, float p) {
  return __builtin_amdgcn_exp2f(p * __builtin_amdgcn_logf(x));
}
__device__ __forceinline__ void gl_lds16(const ushort_t* g, ushort_t* l) {
  __builtin_amdgcn_global_load_lds((const __attribute__((address_space(1))) void*)g,
                                   (__attribute__((address_space(3))) void*)l, 16, 0, 0);
}

// ---------------------------------------------------------------- zero
__global__ void zero_kernel(float* __restrict__ p, int n) {
  int i = blockIdx.x * blockDim.x + threadIdx.x;
  if (i < n) p[i] = 0.f;
}

// ---------------------------------------------------------------- 1/softplus(scale), 512 values
__global__ void sp_kernel(const float* __restrict__ scale, float* __restrict__ inv_s) {
  int i = blockIdx.x * blockDim.x + threadIdx.x;
  if (i < 512) {
    float sc = scale[i];
    float s = (sc > 20.f) ? sc : log1pf(expf(sc));
    inv_s[i] = 1.0f / s;
  }
}

// ---------------------------------------------------------------- fp32 -> bf16 hi/lo planes
__global__ __launch_bounds__(256) void wsplit_kernel(const float* __restrict__ in,
                                                     ushort_t* __restrict__ hi,
                                                     ushort_t* __restrict__ lo, int n4) {
  int i = blockIdx.x * blockDim.x + threadIdx.x;
  const int stride = gridDim.x * blockDim.x;
  for (; i < n4; i += stride) {
    float4 v = ((const float4*)in)[i];
    ushort4 h, l;
    h.x = f2bf(v.x); l.x = f2bf(v.x - bf2f(h.x));
    h.y = f2bf(v.y); l.y = f2bf(v.y - bf2f(h.y));
    h.z = f2bf(v.z); l.z = f2bf(v.z - bf2f(h.z));
    h.w = f2bf(v.w); l.w = f2bf(v.w - bf2f(h.w));
    ((ushort4*)hi)[i] = h;
    ((ushort4*)lo)[i] = l;
  }
}

// ---------------------------------------------------------------- split-bf16 MFMA GEMM
// C[M x Nout] = A[M x K] * B[Nout x K]^T + bias.
// A fp32 (on-the-fly hi/lo split); B pre-split bf16 planes, staged via
// global_load_lds (double-buffered). 3-pass: Ah*Bh + Ah*Bl + Al*Bh.
// 1-D grid = Mtiles*nY, XCD-aware remap: xcd = id&7 owns a contiguous x
// range, y innermost -> the nY re-reads of each A slice hit that XCD's L2.
__global__ __launch_bounds__(256, 2) void gemm_s3w(const float* __restrict__ A,
                                                   const ushort_t* __restrict__ Bh,
                                                   const ushort_t* __restrict__ Bl,
                                                   const float* __restrict__ bias,
                                                   float* __restrict__ C,
                                                   const int K, const int ldc,
                                                   const int log2nY) {
  __shared__ __align__(16) ushort_t Ash[128 * 32];
  __shared__ __align__(16) ushort_t Asl[128 * 32];
  __shared__ __align__(16) ushort_t Bsh[2][128 * 32];
  __shared__ __align__(16) ushort_t Bsl[2][128 * 32];
  const int t = threadIdx.x;
  const int lane = t & 63;
  const int w = t >> 6;
  const int wr = w >> 1, wc = w & 1;

  // XCD-aware remap (bijective: gridDim.x = Mtiles*nY, Mtiles % 8 == 0)
  const int id = blockIdx.x;
  const int xcd = id & 7, j = id >> 3;
  const int xpc = (gridDim.x >> log2nY) >> 3;        // Mtiles/8
  const int xloc = j >> log2nY, y = j & ((1 << log2nY) - 1);
  const size_t bm = (size_t)(xcd * xpc + xloc) * 128;
  const size_t bn = (size_t)y * 128;

  const int lr  = lane & 15;
  const int lk8 = (((lane >> 4) ^ (lane & 3)) * 8);  // A chunk-XOR read slot
  const int bk8 = (lane >> 4) * 8;                   // B linear read slot

  f32x4 acc[4][4] = {};
  float4 fa[4];

  auto load_A = [&](int k0) {
#pragma unroll
    for (int i = 0; i < 4; ++i) {
      const int idx = i * 256 + t;
      const int row = idx >> 3, c4 = idx & 7;
      fa[i] = *(const float4*)(A + (bm + row) * (size_t)K + k0 + c4 * 4);
    }
  };
  auto store_A = [&]() {
#pragma unroll
    for (int i = 0; i < 4; ++i) {
      const int idx = i * 256 + t;
      const int row = idx >> 3, c4 = idx & 7;
      const int off = row * 32 + ((c4 * 4) ^ ((row & 3) * 8));
      ushort4 h, l;
      h.x = f2bf(fa[i].x); l.x = f2bf(fa[i].x - bf2f(h.x));
      h.y = f2bf(fa[i].y); l.y = f2bf(fa[i].y - bf2f(h.y));
      h.z = f2bf(fa[i].z); l.z = f2bf(fa[i].z - bf2f(h.z));
      h.w = f2bf(fa[i].w); l.w = f2bf(fa[i].w - bf2f(h.w));
      *(ushort4*)&Ash[off] = h;
      *(ushort4*)&Asl[off] = l;
    }
  };
  // wave w stages B rows [w*32, w*32+32) of both planes into buf
  auto stage_B = [&](int k0, int buf) {
    const size_t g = (bn + w * 32 + (lane >> 2)) * (size_t)K + k0 + (lane & 3) * 8;
    gl_lds16(Bh + g,                 &Bsh[buf][(w * 32) * 32]);
    gl_lds16(Bh + g + 16 * (size_t)K, &Bsh[buf][(w * 32 + 16) * 32]);
    gl_lds16(Bl + g,                 &Bsl[buf][(w * 32) * 32]);
    gl_lds16(Bl + g + 16 * (size_t)K, &Bsl[buf][(w * 32 + 16) * 32]);
  };

  const int nsteps = K >> 5;
  load_A(0);
  stage_B(0, 0);
  for (int s = 0; s < nsteps; ++s) {
    __syncthreads();            // drains pending loads; prev readers done
    store_A();
    __syncthreads();            // LDS ready
    const int buf = s & 1;
    bf16x8 ah[4], al[4], bh[4], bl[4];
#pragma unroll
    for (int i = 0; i < 4; ++i) {
      ah[i] = *(const bf16x8*)&Ash[(wr * 64 + i * 16 + lr) * 32 + lk8];
      al[i] = *(const bf16x8*)&Asl[(wr * 64 + i * 16 + lr) * 32 + lk8];
      bh[i] = *(const bf16x8*)&Bsh[buf][(wc * 64 + i * 16 + lr) * 32 + bk8];
      bl[i] = *(const bf16x8*)&Bsl[buf][(wc * 64 + i * 16 + lr) * 32 + bk8];
    }
    if (s + 1 < nsteps) {       // prefetch under MFMA (drained at next sync1)
      load_A((s + 1) << 5);
      stage_B((s + 1) << 5, buf ^ 1);
    }
#pragma unroll
    for (int mi = 0; mi < 4; ++mi)
#pragma unroll
      for (int ni = 0; ni < 4; ++ni) {
        acc[mi][ni] = __builtin_amdgcn_mfma_f32_16x16x32_bf16(ah[mi], bh[ni], acc[mi][ni], 0, 0, 0);
        acc[mi][ni] = __builtin_amdgcn_mfma_f32_16x16x32_bf16(ah[mi], bl[ni], acc[mi][ni], 0, 0, 0);
        acc[mi][ni] = __builtin_amdgcn_mfma_f32_16x16x32_bf16(al[mi], bh[ni], acc[mi][ni], 0, 0, 0);
      }
  }

  // epilogue: C/D layout col=lane&15, row=(lane>>4)*4+reg (m89-verified)
  const int rg = (lane >> 4) << 2;
#pragma unroll
  for (int ni = 0; ni < 4; ++ni) {
    const int col = (int)bn + wc * 64 + ni * 16 + lr;
    const float bs = bias[col];
#pragma unroll
    for (int mi = 0; mi < 4; ++mi) {
      float* Cp = C + (bm + wr * 64 + mi * 16 + rg) * (size_t)ldc + col;
#pragma unroll
      for (int j2 = 0; j2 < 4; ++j2)
        Cp[(size_t)j2 * ldc] = acc[mi][ni][j2] + bs;
    }
  }
}

// ---------------------------------------------------------------- nonlinearity, wave-per-row (shfl-only)
__global__ __launch_bounds__(256) void nonlin2_kernel(float* __restrict__ q,
                                                      float* __restrict__ kv,
                                                      const float* __restrict__ inv_s,
                                                      const float* __restrict__ ff) {
  const int t = threadIdx.x, lane = t & 63, w = t >> 6;
  const int row = blockIdx.x * 4 + w;
  float* qr = q + (size_t)row * 512 + lane * 8;
  float* kr = kv + (size_t)row * 1024 + lane * 8;

  float qv[8], kval[8], is[8], fv[8];
  *(float4*)&qv[0] = *(const float4*)qr;       *(float4*)&qv[4] = *(const float4*)(qr + 4);
  *(float4*)&kval[0] = *(const float4*)kr;     *(float4*)&kval[4] = *(const float4*)(kr + 4);
  *(float4*)&is[0] = *(const float4*)(inv_s + lane * 8);
  *(float4*)&is[4] = *(const float4*)(inv_s + lane * 8 + 4);
  *(float4*)&fv[0] = *(const float4*)(ff + lane * 8);
  *(float4*)&fv[4] = *(const float4*)(ff + lane * 8 + 4);

  float sq = 0.f, sk = 0.f;
#pragma unroll
  for (int i = 0; i < 8; ++i) {
    qv[i] = (fmaxf(qv[i], 0.f) + 1e-6f) * is[i];
    kval[i] = (fmaxf(kval[i], 0.f) + 1e-6f) * is[i];
    sq += qv[i] * qv[i];
    sk += kval[i] * kval[i];
  }
#pragma unroll
  for (int off = 1; off < 64; off <<= 1) {
    sq += __shfl_xor(sq, off);
    sk += __shfl_xor(sk, off);
  }
  const float qn = sqrtf(sq), kn = sqrtf(sk);

  float pq[8], pk[8], sq2 = 0.f, sk2 = 0.f;
#pragma unroll
  for (int i = 0; i < 8; ++i) {
    pq[i] = fast_pow(qv[i], fv[i]);
    pk[i] = fast_pow(kval[i], fv[i]);
    sq2 += pq[i] * pq[i];
    sk2 += pk[i] * pk[i];
  }
#pragma unroll
  for (int off = 1; off < 64; off <<= 1) {
    sq2 += __shfl_xor(sq2, off);
    sk2 += __shfl_xor(sk2, off);
  }
  const float qs = qn / sqrtf(sq2), ks = kn / sqrtf(sk2);
#pragma unroll
  for (int i = 0; i < 8; ++i) { qv[i] = pq[i] * qs; kval[i] = pk[i] * ks; }
  *(float4*)qr = *(float4*)&qv[0];       *(float4*)(qr + 4) = *(float4*)&qv[4];
  *(float4*)kr = *(float4*)&kval[0];     *(float4*)(kr + 4) = *(float4*)&kval[4];
}

// ---------------------------------------------------------------- k sum over N
__global__ __launch_bounds__(256) void kmean_kernel(const float* __restrict__ kv,
                                                    float* __restrict__ ksum) {
  const int b = blockIdx.y, ch = blockIdx.x, t = threadIdx.x;
  size_t base = ((size_t)b * N_TOK + (size_t)ch * 128) * 1024;
  float a0 = 0.f, a1 = 0.f;
  for (int i = 0; i < 128; ++i) {
    const float* r = kv + base + (size_t)i * 1024;
    a0 += r[t];
    a1 += r[t + 256];
  }
  atomicAdd(&ksum[b * 512 + t], a0);
  atomicAdd(&ksum[b * 512 + t + 256], a1);
}

// ---------------------------------------------------------------- kv_mat[bh] = k^T v / N
__global__ __launch_bounds__(256) void kvmat_kernel(const float* __restrict__ kv,
                                                    float* __restrict__ kvm) {
  __shared__ float ks[8][64];
  __shared__ float vs[8][64];
  const int bh = blockIdx.y;
  const int b = bh >> 3, h = bh & 7;
  const int chunk = blockIdx.x;
  const int t = threadIdx.x;
  const int tr = (t >> 4) * 4, tc = (t & 15) * 4;
  float acc[4][4] = {};
  size_t rowbase = (size_t)b * N_TOK + (size_t)chunk * 512;
  for (int it = 0; it < 64; ++it) {
    __syncthreads();
#pragma unroll
    for (int l = 0; l < 4; ++l) {
      int idx = l * 256 + t;
      int ri = idx >> 7, ci = idx & 127;
      size_t g = (rowbase + it * 8 + ri) * 1024 + h * 64;
      if (ci < 64) ks[ri][ci] = kv[g + ci];
      else         vs[ri][ci - 64] = kv[g + 512 + (ci - 64)];
    }
    __syncthreads();
#pragma unroll
    for (int ri = 0; ri < 8; ++ri) {
      float a[4], v4[4];
#pragma unroll
      for (int i = 0; i < 4; ++i) a[i] = ks[ri][tr + i];
#pragma unroll
      for (int j = 0; j < 4; ++j) v4[j] = vs[ri][tc + j];
#pragma unroll
      for (int i = 0; i < 4; ++i)
#pragma unroll
        for (int j = 0; j < 4; ++j)
          acc[i][j] = fmaf(a[i], v4[j], acc[i][j]);
    }
  }
  const float scl = 1.0f / (float)N_TOK;
#pragma unroll
  for (int i = 0; i < 4; ++i)
#pragma unroll
    for (int j = 0; j < 4; ++j)
      atomicAdd(&kvm[(size_t)bh * 4096 + (tr + i) * 64 + (tc + j)], acc[i][j] * scl);
}

// ---------------------------------------------------------------- attn with fused z: q <- (q @ kvm) * z
__global__ __launch_bounds__(256) void attn_fz_kernel(float* __restrict__ q,
                                                      const float* __restrict__ kvm,
                                                      const float* __restrict__ ksum) {
  __shared__ float km[64][64];
  __shared__ float qs[64][64];
  __shared__ float kms[64];
  __shared__ float zl[64];
  const int bh = blockIdx.y;
  const int b = bh >> 3, h = bh & 7;
  const int tok0 = blockIdx.x * 64;
  const int t = threadIdx.x;
  const size_t kvm_base = (size_t)bh * 4096;
  const size_t qbase = ((size_t)b * N_TOK + tok0) * 512 + h * 64;
#pragma unroll
  for (int i = 0; i < 16; ++i) {
    int idx = i * 256 + t;
    km[idx >> 6][idx & 63] = kvm[kvm_base + idx];
    qs[idx >> 6][idx & 63] = q[qbase + (size_t)(idx >> 6) * 512 + (idx & 63)];
  }
  if (t < 64) kms[t] = ksum[b * 512 + h * 64 + t];
  __syncthreads();

  // z = 1/(q . (ksum/N) + 1e-6): token t>>2, d-quarter (t&3)*16
  {
    const int tok = t >> 2, dq = (t & 3) * 16;
    float p = 0.f;
#pragma unroll
    for (int i = 0; i < 16; ++i) p += qs[tok][dq + i] * kms[dq + i];
    p += __shfl_xor(p, 1);
    p += __shfl_xor(p, 2);
    if ((t & 3) == 0) zl[tok] = 1.0f / (p * (1.0f / (float)N_TOK) + 1e-6f);
  }
  __syncthreads();

  const int d = t & 63, slot = t >> 6;
  for (int i = 0; i < 16; ++i) {
    const int tok = i * 4 + slot;
    float a0 = 0.f, a1 = 0.f, a2 = 0.f, a3 = 0.f;
#pragma unroll
    for (int din = 0; din < 64; din += 4) {
      a0 = fmaf(qs[tok][din + 0], km[din + 0][d], a0);
      a1 = fmaf(qs[tok][din + 1], km[din + 1][d], a1);
      a2 = fmaf(qs[tok][din + 2], km[din + 2][d], a2);
      a3 = fmaf(qs[tok][din + 3], km[din + 3][d], a3);
    }
    q[qbase + (size_t)tok * 512 + d] = ((a0 + a1) + (a2 + a3)) * zl[tok];
  }
}

// ---------------------------------------------------------------- depthwise 5x5 conv on v, += into y
__global__ __launch_bounds__(256) void conv_kernel(const float* __restrict__ kv,
                                                   float* __restrict__ y,
                                                   const float* __restrict__ wconv,
                                                   const float* __restrict__ bconv) {
  __shared__ float vt[20 * 20 * 32];
  const int zidx = blockIdx.z;
  const int bh = zidx >> 1, chalf = zidx & 1;
  const int b = bh >> 3, h = bh & 7;
  const int c0 = chalf * 32;
  const int tx0 = blockIdx.x * 16, ty0 = blockIdx.y * 16;
  const int t = threadIdx.x;
  const int c = t & 31;
  const size_t vbase = (size_t)b * N_TOK * 1024 + 512 + h * 64 + c0 + c;
  for (int i = 0; i < 50; ++i) {
    int idx = i * 256 + t;
    int pix = idx >> 5;
    int lx = pix % 20, ly = pix / 20;
    int gx = tx0 + lx - 2, gy = ty0 + ly - 2;
    float val = 0.f;
    if ((unsigned)gx < 128u && (unsigned)gy < 128u)
      val = kv[vbase + ((size_t)(gy * 128 + gx)) * 1024 - (size_t)c + (size_t)(idx & 31)];
    vt[pix * 32 + (idx & 31)] = val;
  }
  const int dd = c0 + c;
  float w[25];
#pragma unroll
  for (int k = 0; k < 25; ++k) w[k] = wconv[dd * 25 + k];
  const float bb = bconv[dd];
  __syncthreads();
  const int slot = t >> 5;
  for (int i = 0; i < 32; ++i) {
    const int pix = i * 8 + slot;
    const int px = pix & 15, py = pix >> 4;
    float acc = bb;
#pragma unroll
    for (int ky = 0; ky < 5; ++ky)
#pragma unroll
      for (int kx = 0; kx < 5; ++kx)
        acc = fmaf(w[ky * 5 + kx], vt[((py + ky) * 20 + (px + kx)) * 32 + c], acc);
    size_t o = ((size_t)b * N_TOK + (size_t)(ty0 + py) * 128 + (tx0 + px)) * 512 + h * 64 + dd;
    y[o] += acc;
  }
}

// ---------------------------------------------------------------- launch
extern "C" void kernel_launch(void* const* d_in, const int* in_sizes, int n_in,
                              void* d_out, int out_size, void* d_ws, size_t ws_size,
                              hipStream_t stream) {
  (void)n_in; (void)out_size;
  const float* x     = (const float*)d_in[0];
  const float* Wq    = (const float*)d_in[1];
  const float* bq    = (const float*)d_in[2];
  const float* Wkv   = (const float*)d_in[3];
  const float* bkv   = (const float*)d_in[4];
  const float* Wp    = (const float*)d_in[5];
  const float* bp    = (const float*)d_in[6];
  const float* ff    = (const float*)d_in[7];
  const float* scale = (const float*)d_in[8];
  const float* dwc_w = (const float*)d_in[9];
  const float* dwc_b = (const float*)d_in[10];

  const int B = in_sizes[0] / (N_TOK * CDIM);   // 4
  const int M = B * N_TOK;                      // 65536

  // workspace layout: identical to the round-1 known-good 405.3 MB footprint
  float* q    = (float*)d_ws;                          // M x 512
  float* kv   = q + (size_t)M * 512;                   // M x 1024 (k | v)
  float* ksum = kv + (size_t)M * 1024;                 // B x 512
  float* kvm  = ksum + (size_t)B * 512;                // 32 x 64 x 64
  float* z    = kvm + (size_t)B * 8 * 4096;            // 2 MB, now scratch only

  size_t need = ((size_t)M * 1536 + (size_t)B * 512 + (size_t)B * 8 * 4096 +
                 (size_t)B * 8 * N_TOK) * sizeof(float);
  if (ws_size < need) {
    fprintf(stderr, "kernel_launch: ws too small (%zu < %zu)\n", ws_size, need);
    return;
  }

  // scratch carve-outs (no new ws):
  //  - z region (z_kernel eliminated): wp planes (1 MB) + inv_s (2 KB)
  //  - d_out head (free until final GEMM): wq/wkv planes (3 MB)
  ushort_t* wph  = (ushort_t*)z;                 // 512x512
  ushort_t* wpl  = wph + 262144;
  float*    inv_s = z + 262144;                  // after 524288 ushorts = 1 MB
  ushort_t* wqh  = (ushort_t*)d_out;             // 512x512
  ushort_t* wql  = wqh + 262144;
  ushort_t* wkvh = wql + 262144;                 // 1024x512
  ushort_t* wkvl = wkvh + 524288;

  const int nsmall = B * 512 + B * 8 * 4096;
  zero_kernel<<<(nsmall + 255) / 256, 256, 0, stream>>>(ksum, nsmall);
  sp_kernel<<<2, 256, 0, stream>>>(scale, inv_s);
  wsplit_kernel<<<64, 256, 0, stream>>>(Wq, wqh, wql, 512 * 512 / 4);
  wsplit_kernel<<<128, 256, 0, stream>>>(Wkv, wkvh, wkvl, 1024 * 512 / 4);
  wsplit_kernel<<<64, 256, 0, stream>>>(Wp, wph, wpl, 512 * 512 / 4);

  gemm_s3w<<<(M / 128) * 4, 256, 0, stream>>>(x, wqh, wql, bq, q, CDIM, 512, 2);
  gemm_s3w<<<(M / 128) * 8, 256, 0, stream>>>(x, wkvh, wkvl, bkv, kv, CDIM, 1024, 3);

  nonlin2_kernel<<<M / 4, 256, 0, stream>>>(q, kv, inv_s, ff);
  kmean_kernel<<<dim3(128, B), 256, 0, stream>>>(kv, ksum);
  kvmat_kernel<<<dim3(32, B * 8), 256, 0, stream>>>(kv, kvm);
  attn_fz_kernel<<<dim3(N_TOK / 64, B * 8), 256, 0, stream>>>(q, kvm, ksum);
  conv_kernel<<<dim3(8, 8, B * 8 * 2), 256, 0, stream>>>(kv, q, dwc_w, dwc_b);

  gemm_s3w<<<(M / 128) * 4, 256, 0, stream>>>(q, wph, wpl, bp, (float*)d_out, CDIM, 512, 2);
}